// Round 3
// baseline (658.810 us; speedup 1.0000x reference)
//
#include <hip/hip_runtime.h>

#define N_NODES 100000
#define N_EDGES 800000

typedef unsigned short u16;
typedef unsigned int u32;
typedef __attribute__((ext_vector_type(8))) short short8;
typedef __attribute__((ext_vector_type(4))) float floatx4;

__device__ __forceinline__ float bf2f(u16 u) {
    union { u32 i; float f; } v; v.i = ((u32)u) << 16; return v.f;
}
__device__ __forceinline__ u16 f2bf(float f) {
    union { float f; u32 i; } v; v.f = f;
    u32 r = (v.i + 0x7FFFu + ((v.i >> 16) & 1u)) >> 16;
    return (u16)r;
}
__device__ __forceinline__ float fast_tanh(float x) {
    // tanh(x) = 1 - 2/(exp(2x)+1); hw exp + fast rcp (~1e-6 rel, plenty for bf16 path)
    float e = __expf(2.0f * x);
    return 1.0f - 2.0f * __builtin_amdgcn_rcpf(e + 1.0f);
}

// ---------------- degree + CSR build ----------------

__global__ void k_zero(int* out_deg, int* in_deg) {
    int i = blockIdx.x * 256 + threadIdx.x;
    if (i < N_NODES) { out_deg[i] = 0; in_deg[i] = 0; }
}

__global__ void k_deg(const int* __restrict__ src, const int* __restrict__ dst,
                      int* out_deg, int* in_deg) {
    int e = blockIdx.x * 256 + threadIdx.x;
    if (e < N_EDGES) {
        atomicAdd(&out_deg[src[e]], 1);
        atomicAdd(&in_deg[dst[e]], 1);
    }
}

__global__ void k_scan1(const int* __restrict__ in_deg, int* blockSums) {
    __shared__ int red[256];
    int t = threadIdx.x;
    int base = blockIdx.x * 1024 + t * 4;
    int s = 0;
#pragma unroll
    for (int j = 0; j < 4; j++) { int idx = base + j; if (idx < N_NODES) s += in_deg[idx]; }
    red[t] = s; __syncthreads();
    for (int off = 128; off > 0; off >>= 1) {
        if (t < off) red[t] += red[t + off];
        __syncthreads();
    }
    if (t == 0) blockSums[blockIdx.x] = red[0];
}

__global__ void k_scan2(int* blockSums, int nb, int* csr_pad) {
    if (threadIdx.x == 0) {
        int acc = 0;
        for (int i = 0; i < nb; i++) { int v = blockSums[i]; blockSums[i] = acc; acc += v; }
        *csr_pad = 0;  // zero the csr_edge overread slot
    }
}

__global__ void k_scan3(const int* __restrict__ in_deg, const int* __restrict__ out_deg,
                        const int* __restrict__ blockSums,
                        int* csr_start, int* cursor, float* out_scale, float* in_scale) {
    __shared__ int sc[256];
    int t = threadIdx.x;
    int base = blockIdx.x * 1024 + t * 4;
    int d[4]; int s = 0;
#pragma unroll
    for (int j = 0; j < 4; j++) { int idx = base + j; d[j] = (idx < N_NODES) ? in_deg[idx] : 0; s += d[j]; }
    sc[t] = s; __syncthreads();
    for (int off = 1; off < 256; off <<= 1) {
        int v = (t >= off) ? sc[t - off] : 0;
        __syncthreads();
        sc[t] += v;
        __syncthreads();
    }
    int excl = sc[t] - s;
    int run = blockSums[blockIdx.x] + excl;
#pragma unroll
    for (int j = 0; j < 4; j++) {
        int idx = base + j;
        if (idx < N_NODES) {
            csr_start[idx] = run; cursor[idx] = run; run += d[j];
            int od = out_deg[idx]; if (od < 1) od = 1;
            out_scale[idx] = rsqrtf((float)od);
            int id = d[j]; if (id < 1) id = 1;
            in_scale[idx] = rsqrtf((float)id);
        }
    }
}

__global__ void k_scatter(const int* __restrict__ src, const int* __restrict__ dst,
                          const int* __restrict__ attr, int* cursor, int* csr_edge) {
    int e = blockIdx.x * 256 + threadIdx.x;
    if (e < N_EDGES) {
        int d = dst[e];
        int pos = atomicAdd(&cursor[d], 1);
        csr_edge[pos] = (src[e] << 5) | attr[e];
    }
}

// ---------------- fused node GEMMs: h_sum = feat_src@w1, h_prod = tanh(feat_src@w2 + bias) ----------------
// A-frag (16x16x32): A[m=lane&15][k=quad*8+j]; B[k][n=lane&15], k=quad*8+j; D: row=quad*4+reg, col=lane&15.
// 512 thr = 8 waves -> 128-node block tile; LDS 64KB -> 2 blocks/CU -> 16 waves/CU if VGPR<=128.

__global__ __launch_bounds__(512, 4) void k_gemm(const float* __restrict__ feat,
                                                 const float* __restrict__ w1, const float* __restrict__ w2,
                                                 const float* __restrict__ out_scale,
                                                 u16* __restrict__ h_sum, u16* __restrict__ h_prod) {
    __shared__ u16 ldsw[2 * 8 * 4 * 64 * 8];  // 64 KB, B-frag layout [mat][ot][ks][lane][j], bf16
    for (int idx = threadIdx.x; idx < 2 * 16384; idx += 512) {
        int m = idx >> 14; int r = idx & 16383;
        int k = r >> 7, o = r & 127;
        float val = m ? w2[k * 128 + o] : w1[k * 128 + o];
        int ot = o >> 4, ks = k >> 5, quad = (k >> 3) & 3, j = k & 7;
        int lane = (quad << 4) | (o & 15);
        ldsw[((((m * 8 + ot) * 4 + ks) * 64) + lane) * 8 + j] = f2bf(val);
    }
    __syncthreads();
    int wave = threadIdx.x >> 6, lane = threadIdx.x & 63;
    int quad = lane >> 4, l15 = lane & 15;
    const int NT = (N_NODES + 127) / 128;
    for (int tile = blockIdx.x; tile < NT; tile += gridDim.x) {
        int nb = tile * 128 + wave * 16;
        short8 a[4];
        int anode = nb + l15; if (anode >= N_NODES) anode = N_NODES - 1;
#pragma unroll
        for (int ks = 0; ks < 4; ks++) {
            const float* ap = feat + anode * 128 + ks * 32 + quad * 8;
            float4 f0 = *(const float4*)ap;
            float4 f1 = *(const float4*)(ap + 4);
            short8 av;
            av[0] = (short)f2bf(f0.x); av[1] = (short)f2bf(f0.y);
            av[2] = (short)f2bf(f0.z); av[3] = (short)f2bf(f0.w);
            av[4] = (short)f2bf(f1.x); av[5] = (short)f2bf(f1.y);
            av[6] = (short)f2bf(f1.z); av[7] = (short)f2bf(f1.w);
            a[ks] = av;
        }
        float scl[4];
#pragma unroll
        for (int r = 0; r < 4; r++) {
            int node = nb + quad * 4 + r;
            scl[r] = (node < N_NODES) ? out_scale[node] : 1.0f;
        }
#pragma unroll
        for (int m = 0; m < 2; m++) {
            floatx4 acc[8];
#pragma unroll
            for (int ot = 0; ot < 8; ot++) acc[ot] = (floatx4){0.f, 0.f, 0.f, 0.f};
#pragma unroll
            for (int ot = 0; ot < 8; ot++)
#pragma unroll
                for (int ks = 0; ks < 4; ks++) {
                    short8 b = *(const short8*)&ldsw[((((m * 8 + ot) * 4 + ks) * 64) + lane) * 8];
                    acc[ot] = __builtin_amdgcn_mfma_f32_16x16x32_bf16(a[ks], b, acc[ot], 0, 0, 0);
                }
#pragma unroll
            for (int ot = 0; ot < 8; ot++) {
                int o = ot * 16 + l15;
#pragma unroll
                for (int r = 0; r < 4; r++) {
                    int node = nb + quad * 4 + r;
                    if (node < N_NODES) {
                        if (m == 0) {
                            h_sum[node * 128 + o] = f2bf(acc[ot][r] * scl[r]);
                        } else {
                            float bias = w2[128 * 128 + o];
                            h_prod[node * 128 + o] = f2bf(fast_tanh(acc[ot][r] * scl[r] + bias));
                        }
                    }
                }
            }
        }
    }
}

// ---------------- edge stage: per-dst-node sum & product reduction over CSR ----------------
// one node per wave, grid-stride; bond_emb (16 KB f32) is L1-resident -> no LDS, no barrier.
// 1-deep software pipeline over edges; csr_edge padded by 1 zeroed int for the overread.

__global__ __launch_bounds__(256) void k_edge(const int* __restrict__ csr_start, const int* __restrict__ in_deg,
                                              const int* __restrict__ csr_edge,
                                              const u16* __restrict__ h_sum, const u16* __restrict__ h_prod,
                                              const float* __restrict__ bond_emb,
                                              float* __restrict__ out_hs, u16* __restrict__ hp) {
    int wid = (blockIdx.x * 256 + threadIdx.x) >> 6;
    int lane = threadIdx.x & 63;
    int nwaves = (gridDim.x * 256) >> 6;
    for (int n = wid; n < N_NODES; n += nwaves) {
        int start = csr_start[n], deg = in_deg[n];
        float s0 = 0.f, s1 = 0.f, p0 = 1.f, p1 = 1.f;
        // prologue: load edge 0
        int pk = csr_edge[start];
        int sn = pk >> 5, at = pk & 31;
        u32 up = *(const u32*)(h_prod + sn * 128 + 2 * lane);
        u32 us = *(const u32*)(h_sum + sn * 128 + 2 * lane);
        float e0 = bond_emb[at * 128 + 2 * lane];
        float e1 = bond_emb[at * 128 + 2 * lane + 1];
        for (int i = 0; i < deg; i++) {
            // prefetch edge i+1 (overreads 1 past this node's segment; always valid memory)
            int pk2 = csr_edge[start + i + 1];
            int sn2 = pk2 >> 5, at2 = pk2 & 31;
            u32 up2 = *(const u32*)(h_prod + sn2 * 128 + 2 * lane);
            u32 us2 = *(const u32*)(h_sum + sn2 * 128 + 2 * lane);
            float e0n = bond_emb[at2 * 128 + 2 * lane];
            float e1n = bond_emb[at2 * 128 + 2 * lane + 1];
            // consume edge i
            p0 *= bf2f((u16)(up & 0xFFFF)) * e0;
            p1 *= bf2f((u16)(up >> 16)) * e1;
            s0 += bf2f((u16)(us & 0xFFFF)) * e0;
            s1 += bf2f((u16)(us >> 16)) * e1;
            up = up2; us = us2; e0 = e0n; e1 = e1n;
        }
        float2 sv; sv.x = s0; sv.y = s1;
        *(float2*)(out_hs + n * 128 + 2 * lane) = sv;
        u32 pp = ((u32)f2bf(p1) << 16) | (u32)f2bf(p0);
        *(u32*)(hp + n * 128 + 2 * lane) = pp;
    }
}

// ---------------- final: out = (hs + hp@v) * in_scale ; hs lives in d_out ----------------

__global__ __launch_bounds__(512, 4) void k_final(const u16* __restrict__ hp,
                                                  const float* __restrict__ v, const float* __restrict__ in_scale,
                                                  float* __restrict__ out) {
    __shared__ u16 ldsw[8 * 4 * 64 * 8];  // 32 KB
    for (int idx = threadIdx.x; idx < 16384; idx += 512) {
        int k = idx >> 7, o = idx & 127;
        int ot = o >> 4, ks = k >> 5, quad = (k >> 3) & 3, j = k & 7;
        int lane = (quad << 4) | (o & 15);
        ldsw[(((ot * 4 + ks) * 64) + lane) * 8 + j] = f2bf(v[k * 128 + o]);
    }
    __syncthreads();
    int wave = threadIdx.x >> 6, lane = threadIdx.x & 63;
    int quad = lane >> 4, l15 = lane & 15;
    const int NT = (N_NODES + 127) / 128;
    for (int tile = blockIdx.x; tile < NT; tile += gridDim.x) {
        int nb = tile * 128 + wave * 16;
        short8 a[4];
        int anode = nb + l15; if (anode >= N_NODES) anode = N_NODES - 1;
#pragma unroll
        for (int ks = 0; ks < 4; ks++)
            a[ks] = *(const short8*)(hp + anode * 128 + ks * 32 + quad * 8);
        floatx4 acc[8];
#pragma unroll
        for (int ot = 0; ot < 8; ot++) acc[ot] = (floatx4){0.f, 0.f, 0.f, 0.f};
#pragma unroll
        for (int ot = 0; ot < 8; ot++)
#pragma unroll
            for (int ks = 0; ks < 4; ks++) {
                short8 b = *(const short8*)&ldsw[(((ot * 4 + ks) * 64) + lane) * 8];
                acc[ot] = __builtin_amdgcn_mfma_f32_16x16x32_bf16(a[ks], b, acc[ot], 0, 0, 0);
            }
        float scl[4];
#pragma unroll
        for (int r = 0; r < 4; r++) {
            int node = nb + quad * 4 + r;
            scl[r] = (node < N_NODES) ? in_scale[node] : 0.f;
        }
#pragma unroll
        for (int ot = 0; ot < 8; ot++) {
            int o = ot * 16 + l15;
#pragma unroll
            for (int r = 0; r < 4; r++) {
                int node = nb + quad * 4 + r;
                if (node < N_NODES) {
                    float hsv = out[node * 128 + o];          // hs, written by k_edge
                    out[node * 128 + o] = (acc[ot][r] + hsv) * scl[r];
                }
            }
        }
    }
}

extern "C" void kernel_launch(void* const* d_in, const int* in_sizes, int n_in,
                              void* d_out, int out_size, void* d_ws, size_t ws_size,
                              hipStream_t stream) {
    const float* feat = (const float*)d_in[0];
    const int* src = (const int*)d_in[1];
    const int* dst = (const int*)d_in[2];
    const int* attr = (const int*)d_in[3];
    const float* w1 = (const float*)d_in[4];
    const float* w2 = (const float*)d_in[5];
    const float* v = (const float*)d_in[6];
    const float* bond = (const float*)d_in[7];
    float* out = (float*)d_out;

    char* ws = (char*)d_ws;
    size_t off = 0;
    auto alloc = [&](size_t bytes) -> char* {
        char* p = ws + off; off += (bytes + 255) & ~(size_t)255; return p;
    };
    int* out_deg   = (int*)alloc((size_t)N_NODES * 4);
    int* in_deg    = (int*)alloc((size_t)N_NODES * 4);
    int* csr_start = (int*)alloc((size_t)N_NODES * 4);
    int* cursor    = (int*)alloc((size_t)N_NODES * 4);
    int* blockSums = (int*)alloc(1024 * 4);
    float* out_scale = (float*)alloc((size_t)N_NODES * 4);
    float* in_scale  = (float*)alloc((size_t)N_NODES * 4);
    int* csr_edge  = (int*)alloc(((size_t)N_EDGES + 1) * 4);  // +1 pad for pipeline overread
    u16* h_sum  = (u16*)alloc((size_t)N_NODES * 128 * 2);
    u16* h_prod = (u16*)alloc((size_t)N_NODES * 128 * 2);
    u16* hp     = (u16*)alloc((size_t)N_NODES * 128 * 2);

    (void)in_sizes; (void)n_in; (void)out_size; (void)ws_size;

    int nb = (N_NODES + 1023) / 1024;
    k_zero<<<(N_NODES + 255) / 256, 256, 0, stream>>>(out_deg, in_deg);
    k_deg<<<(N_EDGES + 255) / 256, 256, 0, stream>>>(src, dst, out_deg, in_deg);
    k_scan1<<<nb, 256, 0, stream>>>(in_deg, blockSums);
    k_scan2<<<1, 64, 0, stream>>>(blockSums, nb, csr_edge + N_EDGES);
    k_scan3<<<nb, 256, 0, stream>>>(in_deg, out_deg, blockSums, csr_start, cursor, out_scale, in_scale);
    k_scatter<<<(N_EDGES + 255) / 256, 256, 0, stream>>>(src, dst, attr, cursor, csr_edge);
    k_gemm<<<512, 512, 0, stream>>>(feat, w1, w2, out_scale, h_sum, h_prod);
    k_edge<<<1024, 256, 0, stream>>>(csr_start, in_deg, csr_edge, h_sum, h_prod, bond, out, hp);
    k_final<<<512, 512, 0, stream>>>(hp, v, in_scale, out);
}

// Round 4
// 591.807 us; speedup vs baseline: 1.1132x; 1.1132x over previous
//
#include <hip/hip_runtime.h>

#define N_NODES 100000
#define N_EDGES 800000

typedef unsigned short u16;
typedef unsigned int u32;
typedef __attribute__((ext_vector_type(8))) short short8;
typedef __attribute__((ext_vector_type(4))) float floatx4;

__device__ __forceinline__ float bf2f(u16 u) {
    union { u32 i; float f; } v; v.i = ((u32)u) << 16; return v.f;
}
__device__ __forceinline__ u16 f2bf(float f) {
    union { float f; u32 i; } v; v.f = f;
    u32 r = (v.i + 0x7FFFu + ((v.i >> 16) & 1u)) >> 16;
    return (u16)r;
}
__device__ __forceinline__ float fast_tanh(float x) {
    float e = __expf(2.0f * x);
    return 1.0f - 2.0f * __builtin_amdgcn_rcpf(e + 1.0f);
}

// ---------------- degree + CSR build ----------------

__global__ void k_zero(int* out_deg, int* in_deg) {
    int i = blockIdx.x * 256 + threadIdx.x;
    if (i < N_NODES) { out_deg[i] = 0; in_deg[i] = 0; }
}

__global__ void k_deg(const int* __restrict__ src, const int* __restrict__ dst,
                      int* out_deg, int* in_deg) {
    int e = blockIdx.x * 256 + threadIdx.x;
    if (e < N_EDGES) {
        atomicAdd(&out_deg[src[e]], 1);
        atomicAdd(&in_deg[dst[e]], 1);
    }
}

__global__ void k_scan1(const int* __restrict__ in_deg, int* blockSums) {
    __shared__ int red[256];
    int t = threadIdx.x;
    int base = blockIdx.x * 1024 + t * 4;
    int s = 0;
#pragma unroll
    for (int j = 0; j < 4; j++) { int idx = base + j; if (idx < N_NODES) s += in_deg[idx]; }
    red[t] = s; __syncthreads();
    for (int off = 128; off > 0; off >>= 1) {
        if (t < off) red[t] += red[t + off];
        __syncthreads();
    }
    if (t == 0) blockSums[blockIdx.x] = red[0];
}

__global__ void k_scan2(int* blockSums, int nb, int* csr_pad) {
    if (threadIdx.x == 0) {
        int acc = 0;
        for (int i = 0; i < nb; i++) { int v = blockSums[i]; blockSums[i] = acc; acc += v; }
        *csr_pad = 0;  // zero the csr_edge overread slot
    }
}

__global__ void k_scan3(const int* __restrict__ in_deg, const int* __restrict__ out_deg,
                        const int* __restrict__ blockSums,
                        int* csr_start, int* cursor, float* out_scale, float* in_scale) {
    __shared__ int sc[256];
    int t = threadIdx.x;
    int base = blockIdx.x * 1024 + t * 4;
    int d[4]; int s = 0;
#pragma unroll
    for (int j = 0; j < 4; j++) { int idx = base + j; d[j] = (idx < N_NODES) ? in_deg[idx] : 0; s += d[j]; }
    sc[t] = s; __syncthreads();
    for (int off = 1; off < 256; off <<= 1) {
        int v = (t >= off) ? sc[t - off] : 0;
        __syncthreads();
        sc[t] += v;
        __syncthreads();
    }
    int excl = sc[t] - s;
    int run = blockSums[blockIdx.x] + excl;
#pragma unroll
    for (int j = 0; j < 4; j++) {
        int idx = base + j;
        if (idx < N_NODES) {
            csr_start[idx] = run; cursor[idx] = run; run += d[j];
            int od = out_deg[idx]; if (od < 1) od = 1;
            out_scale[idx] = rsqrtf((float)od);
            int id = d[j]; if (id < 1) id = 1;
            in_scale[idx] = rsqrtf((float)id);
        }
    }
}

__global__ void k_scatter(const int* __restrict__ src, const int* __restrict__ dst,
                          const int* __restrict__ attr, int* cursor, int* csr_edge) {
    int e = blockIdx.x * 256 + threadIdx.x;
    if (e < N_EDGES) {
        int d = dst[e];
        int pos = atomicAdd(&cursor[d], 1);
        csr_edge[pos] = (src[e] << 5) | attr[e];
    }
}

// ---------------- fused node GEMMs: h_sum = feat_src@w1, h_prod = tanh(feat_src@w2 + bias) ----------------
// A-frag (16x16x32): A[m=lane&15][k=quad*8+j]; B[k][n=lane&15], k=quad*8+j; D: row=quad*4+reg, col=lane&15.
// 512 thr = 8 waves -> 128-node tile; 64 KB LDS -> 2 blocks/CU = 16 waves/CU.
// waves_per_eu(4,4) pins the allocator to the 128-VGPR tier: round-3's (512,4) let it chase the
// 64-VGPR tier and spill acc[] to scratch (FETCH 26->203 MB, WRITE 50->293 MB measured).

__global__ __launch_bounds__(512)
__attribute__((amdgpu_waves_per_eu(4, 4)))
void k_gemm(const float* __restrict__ feat,
            const float* __restrict__ w1, const float* __restrict__ w2,
            const float* __restrict__ out_scale,
            u16* __restrict__ h_sum, u16* __restrict__ h_prod) {
    __shared__ u16 ldsw[2 * 8 * 4 * 64 * 8];  // 64 KB, B-frag layout [mat][ot][ks][lane][j], bf16
    for (int idx = threadIdx.x; idx < 2 * 16384; idx += 512) {
        int m = idx >> 14; int r = idx & 16383;
        int k = r >> 7, o = r & 127;
        float val = m ? w2[k * 128 + o] : w1[k * 128 + o];
        int ot = o >> 4, ks = k >> 5, quad = (k >> 3) & 3, j = k & 7;
        int lane = (quad << 4) | (o & 15);
        ldsw[((((m * 8 + ot) * 4 + ks) * 64) + lane) * 8 + j] = f2bf(val);
    }
    __syncthreads();
    int wave = threadIdx.x >> 6, lane = threadIdx.x & 63;
    int quad = lane >> 4, l15 = lane & 15;
    const int NT = (N_NODES + 127) / 128;
    for (int tile = blockIdx.x; tile < NT; tile += gridDim.x) {
        int nb = tile * 128 + wave * 16;
        short8 a[4];
        int anode = nb + l15; if (anode >= N_NODES) anode = N_NODES - 1;
#pragma unroll
        for (int ks = 0; ks < 4; ks++) {
            const float* ap = feat + anode * 128 + ks * 32 + quad * 8;
            float4 f0 = *(const float4*)ap;
            float4 f1 = *(const float4*)(ap + 4);
            short8 av;
            av[0] = (short)f2bf(f0.x); av[1] = (short)f2bf(f0.y);
            av[2] = (short)f2bf(f0.z); av[3] = (short)f2bf(f0.w);
            av[4] = (short)f2bf(f1.x); av[5] = (short)f2bf(f1.y);
            av[6] = (short)f2bf(f1.z); av[7] = (short)f2bf(f1.w);
            a[ks] = av;
        }
        float scl[4];
#pragma unroll
        for (int r = 0; r < 4; r++) {
            int node = nb + quad * 4 + r;
            scl[r] = (node < N_NODES) ? out_scale[node] : 1.0f;
        }
#pragma unroll
        for (int m = 0; m < 2; m++) {
            floatx4 acc[8];
#pragma unroll
            for (int ot = 0; ot < 8; ot++) acc[ot] = (floatx4){0.f, 0.f, 0.f, 0.f};
#pragma unroll
            for (int ot = 0; ot < 8; ot++)
#pragma unroll
                for (int ks = 0; ks < 4; ks++) {
                    short8 b = *(const short8*)&ldsw[((((m * 8 + ot) * 4 + ks) * 64) + lane) * 8];
                    acc[ot] = __builtin_amdgcn_mfma_f32_16x16x32_bf16(a[ks], b, acc[ot], 0, 0, 0);
                }
#pragma unroll
            for (int ot = 0; ot < 8; ot++) {
                int o = ot * 16 + l15;
#pragma unroll
                for (int r = 0; r < 4; r++) {
                    int node = nb + quad * 4 + r;
                    if (node < N_NODES) {
                        if (m == 0) {
                            h_sum[node * 128 + o] = f2bf(acc[ot][r] * scl[r]);
                        } else {
                            float bias = w2[128 * 128 + o];
                            h_prod[node * 128 + o] = f2bf(fast_tanh(acc[ot][r] * scl[r] + bias));
                        }
                    }
                }
            }
        }
    }
}

// ---------------- edge stage: per-dst-node sum & product reduction over CSR ----------------
// one node per wave, grid-stride; bond_emb (16 KB f32) is L1/L2-resident -> no LDS, no barrier.
// 1-deep software pipeline over edges; csr_edge padded by 1 zeroed int for the overread.

__global__ __launch_bounds__(256, 8) void k_edge(const int* __restrict__ csr_start, const int* __restrict__ in_deg,
                                                 const int* __restrict__ csr_edge,
                                                 const u16* __restrict__ h_sum, const u16* __restrict__ h_prod,
                                                 const float* __restrict__ bond_emb,
                                                 float* __restrict__ out_hs, u16* __restrict__ hp) {
    int wid = (blockIdx.x * 256 + threadIdx.x) >> 6;
    int lane = threadIdx.x & 63;
    int nwaves = (gridDim.x * 256) >> 6;
    for (int n = wid; n < N_NODES; n += nwaves) {
        int start = csr_start[n], deg = in_deg[n];
        float s0 = 0.f, s1 = 0.f, p0 = 1.f, p1 = 1.f;
        int pk = csr_edge[start];
        int sn = pk >> 5, at = pk & 31;
        u32 up = *(const u32*)(h_prod + sn * 128 + 2 * lane);
        u32 us = *(const u32*)(h_sum + sn * 128 + 2 * lane);
        float e0 = bond_emb[at * 128 + 2 * lane];
        float e1 = bond_emb[at * 128 + 2 * lane + 1];
        for (int i = 0; i < deg; i++) {
            int pk2 = csr_edge[start + i + 1];
            int sn2 = pk2 >> 5, at2 = pk2 & 31;
            u32 up2 = *(const u32*)(h_prod + sn2 * 128 + 2 * lane);
            u32 us2 = *(const u32*)(h_sum + sn2 * 128 + 2 * lane);
            float e0n = bond_emb[at2 * 128 + 2 * lane];
            float e1n = bond_emb[at2 * 128 + 2 * lane + 1];
            p0 *= bf2f((u16)(up & 0xFFFF)) * e0;
            p1 *= bf2f((u16)(up >> 16)) * e1;
            s0 += bf2f((u16)(us & 0xFFFF)) * e0;
            s1 += bf2f((u16)(us >> 16)) * e1;
            up = up2; us = us2; e0 = e0n; e1 = e1n;
        }
        float2 sv; sv.x = s0; sv.y = s1;
        *(float2*)(out_hs + n * 128 + 2 * lane) = sv;
        u32 pp = ((u32)f2bf(p1) << 16) | (u32)f2bf(p0);
        *(u32*)(hp + n * 128 + 2 * lane) = pp;
    }
}

// ---------------- final: out = (hs + hp@v) * in_scale ; hs lives in d_out ----------------

__global__ __launch_bounds__(512)
__attribute__((amdgpu_waves_per_eu(4, 4)))
void k_final(const u16* __restrict__ hp,
             const float* __restrict__ v, const float* __restrict__ in_scale,
             float* __restrict__ out) {
    __shared__ u16 ldsw[8 * 4 * 64 * 8];  // 32 KB
    for (int idx = threadIdx.x; idx < 16384; idx += 512) {
        int k = idx >> 7, o = idx & 127;
        int ot = o >> 4, ks = k >> 5, quad = (k >> 3) & 3, j = k & 7;
        int lane = (quad << 4) | (o & 15);
        ldsw[(((ot * 4 + ks) * 64) + lane) * 8 + j] = f2bf(v[k * 128 + o]);
    }
    __syncthreads();
    int wave = threadIdx.x >> 6, lane = threadIdx.x & 63;
    int quad = lane >> 4, l15 = lane & 15;
    const int NT = (N_NODES + 127) / 128;
    for (int tile = blockIdx.x; tile < NT; tile += gridDim.x) {
        int nb = tile * 128 + wave * 16;
        short8 a[4];
        int anode = nb + l15; if (anode >= N_NODES) anode = N_NODES - 1;
#pragma unroll
        for (int ks = 0; ks < 4; ks++)
            a[ks] = *(const short8*)(hp + anode * 128 + ks * 32 + quad * 8);
        floatx4 acc[8];
#pragma unroll
        for (int ot = 0; ot < 8; ot++) acc[ot] = (floatx4){0.f, 0.f, 0.f, 0.f};
#pragma unroll
        for (int ot = 0; ot < 8; ot++)
#pragma unroll
            for (int ks = 0; ks < 4; ks++) {
                short8 b = *(const short8*)&ldsw[(((ot * 4 + ks) * 64) + lane) * 8];
                acc[ot] = __builtin_amdgcn_mfma_f32_16x16x32_bf16(a[ks], b, acc[ot], 0, 0, 0);
            }
        float scl[4];
#pragma unroll
        for (int r = 0; r < 4; r++) {
            int node = nb + quad * 4 + r;
            scl[r] = (node < N_NODES) ? in_scale[node] : 0.f;
        }
#pragma unroll
        for (int ot = 0; ot < 8; ot++) {
            int o = ot * 16 + l15;
#pragma unroll
            for (int r = 0; r < 4; r++) {
                int node = nb + quad * 4 + r;
                if (node < N_NODES) {
                    float hsv = out[node * 128 + o];          // hs, written by k_edge
                    out[node * 128 + o] = (acc[ot][r] + hsv) * scl[r];
                }
            }
        }
    }
}

extern "C" void kernel_launch(void* const* d_in, const int* in_sizes, int n_in,
                              void* d_out, int out_size, void* d_ws, size_t ws_size,
                              hipStream_t stream) {
    const float* feat = (const float*)d_in[0];
    const int* src = (const int*)d_in[1];
    const int* dst = (const int*)d_in[2];
    const int* attr = (const int*)d_in[3];
    const float* w1 = (const float*)d_in[4];
    const float* w2 = (const float*)d_in[5];
    const float* v = (const float*)d_in[6];
    const float* bond = (const float*)d_in[7];
    float* out = (float*)d_out;

    char* ws = (char*)d_ws;
    size_t off = 0;
    auto alloc = [&](size_t bytes) -> char* {
        char* p = ws + off; off += (bytes + 255) & ~(size_t)255; return p;
    };
    int* out_deg   = (int*)alloc((size_t)N_NODES * 4);
    int* in_deg    = (int*)alloc((size_t)N_NODES * 4);
    int* csr_start = (int*)alloc((size_t)N_NODES * 4);
    int* cursor    = (int*)alloc((size_t)N_NODES * 4);
    int* blockSums = (int*)alloc(1024 * 4);
    float* out_scale = (float*)alloc((size_t)N_NODES * 4);
    float* in_scale  = (float*)alloc((size_t)N_NODES * 4);
    int* csr_edge  = (int*)alloc(((size_t)N_EDGES + 1) * 4);  // +1 pad for pipeline overread
    u16* h_sum  = (u16*)alloc((size_t)N_NODES * 128 * 2);
    u16* h_prod = (u16*)alloc((size_t)N_NODES * 128 * 2);
    u16* hp     = (u16*)alloc((size_t)N_NODES * 128 * 2);

    (void)in_sizes; (void)n_in; (void)out_size; (void)ws_size;

    int nb = (N_NODES + 1023) / 1024;
    k_zero<<<(N_NODES + 255) / 256, 256, 0, stream>>>(out_deg, in_deg);
    k_deg<<<(N_EDGES + 255) / 256, 256, 0, stream>>>(src, dst, out_deg, in_deg);
    k_scan1<<<nb, 256, 0, stream>>>(in_deg, blockSums);
    k_scan2<<<1, 64, 0, stream>>>(blockSums, nb, csr_edge + N_EDGES);
    k_scan3<<<nb, 256, 0, stream>>>(in_deg, out_deg, blockSums, csr_start, cursor, out_scale, in_scale);
    k_scatter<<<(N_EDGES + 255) / 256, 256, 0, stream>>>(src, dst, attr, cursor, csr_edge);
    k_gemm<<<512, 512, 0, stream>>>(feat, w1, w2, out_scale, h_sum, h_prod);
    k_edge<<<2048, 256, 0, stream>>>(csr_start, in_deg, csr_edge, h_sum, h_prod, bond, out, hp);
    k_final<<<512, 512, 0, stream>>>(hp, v, in_scale, out);
}

// Round 5
// 436.117 us; speedup vs baseline: 1.5106x; 1.3570x over previous
//
#include <hip/hip_runtime.h>

#define N_NODES 100000
#define N_EDGES 800000

typedef unsigned short u16;
typedef unsigned int u32;
typedef __attribute__((ext_vector_type(8))) short short8;
typedef __attribute__((ext_vector_type(4))) float floatx4;

__device__ __forceinline__ float bf2f(u16 u) {
    union { u32 i; float f; } v; v.i = ((u32)u) << 16; return v.f;
}
__device__ __forceinline__ u16 f2bf(float f) {
    union { float f; u32 i; } v; v.f = f;
    u32 r = (v.i + 0x7FFFu + ((v.i >> 16) & 1u)) >> 16;
    return (u16)r;
}
__device__ __forceinline__ float fast_tanh(float x) {
    float e = __expf(2.0f * x);
    return 1.0f - 2.0f * __builtin_amdgcn_rcpf(e + 1.0f);
}

// ---------------- degree + CSR build ----------------

__global__ void k_deg(const int* __restrict__ src, const int* __restrict__ dst,
                      int* out_deg, int* in_deg) {
    int e = blockIdx.x * 256 + threadIdx.x;
    if (e < N_EDGES) {
        atomicAdd(&out_deg[src[e]], 1);
        atomicAdd(&in_deg[dst[e]], 1);
    }
}

__global__ void k_scan1(const int* __restrict__ in_deg, int* blockSums) {
    __shared__ int red[256];
    int t = threadIdx.x;
    int base = blockIdx.x * 1024 + t * 4;
    int s = 0;
#pragma unroll
    for (int j = 0; j < 4; j++) { int idx = base + j; if (idx < N_NODES) s += in_deg[idx]; }
    red[t] = s; __syncthreads();
    for (int off = 128; off > 0; off >>= 1) {
        if (t < off) red[t] += red[t + off];
        __syncthreads();
    }
    if (t == 0) blockSums[blockIdx.x] = red[0];
}

__global__ void k_scan2(int* blockSums, int nb, int* csr_pad) {
    if (threadIdx.x == 0) {
        int acc = 0;
        for (int i = 0; i < nb; i++) { int v = blockSums[i]; blockSums[i] = acc; acc += v; }
        *csr_pad = 0;  // zero the csr_edge overread slot
    }
}

__global__ void k_scan3(const int* __restrict__ in_deg, const int* __restrict__ out_deg,
                        const int* __restrict__ blockSums,
                        int* csr_start, int* cursor, float* out_scale, float* in_scale) {
    __shared__ int sc[256];
    int t = threadIdx.x;
    int base = blockIdx.x * 1024 + t * 4;
    int d[4]; int s = 0;
#pragma unroll
    for (int j = 0; j < 4; j++) { int idx = base + j; d[j] = (idx < N_NODES) ? in_deg[idx] : 0; s += d[j]; }
    sc[t] = s; __syncthreads();
    for (int off = 1; off < 256; off <<= 1) {
        int v = (t >= off) ? sc[t - off] : 0;
        __syncthreads();
        sc[t] += v;
        __syncthreads();
    }
    int excl = sc[t] - s;
    int run = blockSums[blockIdx.x] + excl;
#pragma unroll
    for (int j = 0; j < 4; j++) {
        int idx = base + j;
        if (idx < N_NODES) {
            csr_start[idx] = run; cursor[idx] = run; run += d[j];
            int od = out_deg[idx]; if (od < 1) od = 1;
            out_scale[idx] = rsqrtf((float)od);
            int id = d[j]; if (id < 1) id = 1;
            in_scale[idx] = rsqrtf((float)id);
        }
    }
}

__global__ void k_scatter(const int* __restrict__ src, const int* __restrict__ dst,
                          const int* __restrict__ attr, int* cursor, int* csr_edge) {
    int e = blockIdx.x * 256 + threadIdx.x;
    if (e < N_EDGES) {
        int d = dst[e];
        int pos = atomicAdd(&cursor[d], 1);
        csr_edge[pos] = (src[e] << 5) | attr[e];
    }
}

// ---------------- prep: weights -> bf16 B-frag layout; feat*scale -> bf16 ----------------
// frag layout [m][ot][ks][lane][j]: element (k,o): ot=o>>4, ks=k>>5, quad=(k>>3)&3, j=k&7, lane=(quad<<4)|(o&15)

__global__ void k_prepw(const float* __restrict__ w1, const float* __restrict__ w2,
                        const float* __restrict__ v, u16* __restrict__ wvfrag) {
    int idx = blockIdx.x * 256 + threadIdx.x;   // 3*16384
    if (idx >= 3 * 16384) return;
    int m = idx >> 14, r = idx & 16383;
    int k = r >> 7, o = r & 127;
    float val = (m == 0) ? w1[k * 128 + o] : (m == 1) ? w2[k * 128 + o] : v[k * 128 + o];
    int ot = o >> 4, ks = k >> 5, quad = (k >> 3) & 3, j = k & 7;
    int lane = (quad << 4) | (o & 15);
    wvfrag[(((m * 8 + ot) * 4 + ks) * 64 + lane) * 8 + j] = f2bf(val);
}

__global__ void k_prepf(const float* __restrict__ feat, const float* __restrict__ out_scale,
                        u16* __restrict__ featb) {
    int gid = blockIdx.x * 256 + threadIdx.x;   // N*32
    int n = gid >> 5, c = gid & 31;
    if (n >= N_NODES) return;
    float s = out_scale[n];
    float4 f = *(const float4*)(feat + n * 128 + c * 4);
    uint2 pv;
    pv.x = (u32)f2bf(f.x * s) | ((u32)f2bf(f.y * s) << 16);
    pv.y = (u32)f2bf(f.z * s) | ((u32)f2bf(f.w * s) << 16);
    *(uint2*)(featb + n * 128 + c * 4) = pv;
}

// ---------------- node GEMMs: hrow[n][0:128]=featb@w1, hrow[n][128:256]=tanh(featb@w2+bias) ----------------
// per-ot accumulator (4 VGPRs) + immediate epilogue => natural pressure ~60, spill-proof at the 64-VGPR tier.
// one matrix per block (blockIdx&1), 32 KB LDS => 5 blocks/CU.

__global__ __launch_bounds__(256) void k_gemm(const u16* __restrict__ featb,
                                              const u16* __restrict__ wvfrag,
                                              const float* __restrict__ w2,
                                              u16* __restrict__ hrow) {
    __shared__ u16 ldsw[16384];  // 32 KB
    int m = blockIdx.x & 1;
    const u16* wsrc = wvfrag + m * 16384;
    for (int i = threadIdx.x; i < 2048; i += 256)
        ((ulonglong2*)ldsw)[i] = ((const ulonglong2*)wsrc)[i];
    __syncthreads();
    int wave = threadIdx.x >> 6, lane = threadIdx.x & 63;
    int quad = lane >> 4, l15 = lane & 15;
    const float* bias = w2 + 128 * 128;
    const int NT = (N_NODES + 63) / 64;
    int stride = gridDim.x >> 1;
    for (int tile = blockIdx.x >> 1; tile < NT; tile += stride) {
        int nb = tile * 64 + wave * 16;
        int anode = nb + l15; if (anode >= N_NODES) anode = N_NODES - 1;
        short8 a[4];
#pragma unroll
        for (int ks = 0; ks < 4; ks++)
            a[ks] = *(const short8*)(featb + anode * 128 + ks * 32 + quad * 8);
#pragma unroll
        for (int ot = 0; ot < 8; ot++) {
            floatx4 acc = (floatx4){0.f, 0.f, 0.f, 0.f};
#pragma unroll
            for (int ks = 0; ks < 4; ks++) {
                short8 b = *(const short8*)&ldsw[((ot * 4 + ks) * 64 + lane) * 8];
                acc = __builtin_amdgcn_mfma_f32_16x16x32_bf16(a[ks], b, acc, 0, 0, 0);
            }
            int o = ot * 16 + l15;
            if (m == 0) {
#pragma unroll
                for (int r = 0; r < 4; r++) {
                    int node = nb + quad * 4 + r;
                    if (node < N_NODES) hrow[node * 256 + o] = f2bf(acc[r]);
                }
            } else {
                float bs = bias[o];
#pragma unroll
                for (int r = 0; r < 4; r++) {
                    int node = nb + quad * 4 + r;
                    if (node < N_NODES) hrow[node * 256 + 128 + o] = f2bf(fast_tanh(acc[r] + bs));
                }
            }
        }
    }
}

// ---------------- edge stage: per-dst-node sum & product reduction over CSR ----------------
// one node per wave, grid-stride; bond_emb (16 KB f32) L1/L2-resident; 1-deep pipeline.

__global__ __launch_bounds__(256, 8) void k_edge(const int* __restrict__ csr_start, const int* __restrict__ in_deg,
                                                 const int* __restrict__ csr_edge,
                                                 const u16* __restrict__ hrow,
                                                 const float* __restrict__ bond_emb,
                                                 float* __restrict__ out_hs, u16* __restrict__ hp) {
    int wid = (blockIdx.x * 256 + threadIdx.x) >> 6;
    int lane = threadIdx.x & 63;
    int nwaves = (gridDim.x * 256) >> 6;
    for (int n = wid; n < N_NODES; n += nwaves) {
        int start = csr_start[n], deg = in_deg[n];
        float s0 = 0.f, s1 = 0.f, p0 = 1.f, p1 = 1.f;
        int pk = csr_edge[start];
        int sn = pk >> 5, at = pk & 31;
        const u16* base = hrow + sn * 256;
        u32 us = *(const u32*)(base + 2 * lane);
        u32 up = *(const u32*)(base + 128 + 2 * lane);
        float e0 = bond_emb[at * 128 + 2 * lane];
        float e1 = bond_emb[at * 128 + 2 * lane + 1];
        for (int i = 0; i < deg; i++) {
            int pk2 = csr_edge[start + i + 1];
            int sn2 = pk2 >> 5, at2 = pk2 & 31;
            const u16* base2 = hrow + sn2 * 256;
            u32 us2 = *(const u32*)(base2 + 2 * lane);
            u32 up2 = *(const u32*)(base2 + 128 + 2 * lane);
            float e0n = bond_emb[at2 * 128 + 2 * lane];
            float e1n = bond_emb[at2 * 128 + 2 * lane + 1];
            p0 *= bf2f((u16)(up & 0xFFFF)) * e0;
            p1 *= bf2f((u16)(up >> 16)) * e1;
            s0 += bf2f((u16)(us & 0xFFFF)) * e0;
            s1 += bf2f((u16)(us >> 16)) * e1;
            up = up2; us = us2; e0 = e0n; e1 = e1n;
        }
        float2 sv; sv.x = s0; sv.y = s1;
        *(float2*)(out_hs + n * 128 + 2 * lane) = sv;
        u32 pp = ((u32)f2bf(p1) << 16) | (u32)f2bf(p0);
        *(u32*)(hp + n * 128 + 2 * lane) = pp;
    }
}

// ---------------- final: out = (hs + hp@v) * in_scale ; hs lives in d_out ----------------

__global__ __launch_bounds__(256) void k_final(const u16* __restrict__ hp,
                                               const u16* __restrict__ vfrag,
                                               const float* __restrict__ in_scale,
                                               float* __restrict__ out) {
    __shared__ u16 ldsw[16384];  // 32 KB
    for (int i = threadIdx.x; i < 2048; i += 256)
        ((ulonglong2*)ldsw)[i] = ((const ulonglong2*)vfrag)[i];
    __syncthreads();
    int wave = threadIdx.x >> 6, lane = threadIdx.x & 63;
    int quad = lane >> 4, l15 = lane & 15;
    const int NT = (N_NODES + 63) / 64;
    for (int tile = blockIdx.x; tile < NT; tile += gridDim.x) {
        int nb = tile * 64 + wave * 16;
        int anode = nb + l15; if (anode >= N_NODES) anode = N_NODES - 1;
        short8 a[4];
#pragma unroll
        for (int ks = 0; ks < 4; ks++)
            a[ks] = *(const short8*)(hp + anode * 128 + ks * 32 + quad * 8);
#pragma unroll
        for (int ot = 0; ot < 8; ot++) {
            floatx4 acc = (floatx4){0.f, 0.f, 0.f, 0.f};
#pragma unroll
            for (int ks = 0; ks < 4; ks++) {
                short8 b = *(const short8*)&ldsw[((ot * 4 + ks) * 64 + lane) * 8];
                acc = __builtin_amdgcn_mfma_f32_16x16x32_bf16(a[ks], b, acc, 0, 0, 0);
            }
            int o = ot * 16 + l15;
#pragma unroll
            for (int r = 0; r < 4; r++) {
                int node = nb + quad * 4 + r;
                if (node < N_NODES) {
                    float scl = in_scale[node];
                    float hsv = out[node * 128 + o];          // hs, written by k_edge
                    out[node * 128 + o] = (acc[r] + hsv) * scl;
                }
            }
        }
    }
}

extern "C" void kernel_launch(void* const* d_in, const int* in_sizes, int n_in,
                              void* d_out, int out_size, void* d_ws, size_t ws_size,
                              hipStream_t stream) {
    const float* feat = (const float*)d_in[0];
    const int* src = (const int*)d_in[1];
    const int* dst = (const int*)d_in[2];
    const int* attr = (const int*)d_in[3];
    const float* w1 = (const float*)d_in[4];
    const float* w2 = (const float*)d_in[5];
    const float* v = (const float*)d_in[6];
    const float* bond = (const float*)d_in[7];
    float* out = (float*)d_out;

    char* ws = (char*)d_ws;
    size_t off = 0;
    auto alloc = [&](size_t bytes) -> char* {
        char* p = ws + off; off += (bytes + 255) & ~(size_t)255; return p;
    };
    int* deg2      = (int*)alloc((size_t)2 * N_NODES * 4);   // out_deg | in_deg, one memset
    int* out_deg   = deg2;
    int* in_deg    = deg2 + N_NODES;
    int* csr_start = (int*)alloc((size_t)N_NODES * 4);
    int* cursor    = (int*)alloc((size_t)N_NODES * 4);
    int* blockSums = (int*)alloc(1024 * 4);
    float* out_scale = (float*)alloc((size_t)N_NODES * 4);
    float* in_scale  = (float*)alloc((size_t)N_NODES * 4);
    int* csr_edge  = (int*)alloc(((size_t)N_EDGES + 1) * 4);  // +1 pad for pipeline overread
    u16* wvfrag = (u16*)alloc((size_t)3 * 16384 * 2);         // w1|w2|v bf16 frags
    u16* featb  = (u16*)alloc((size_t)N_NODES * 128 * 2);     // feat*out_scale, bf16
    u16* hrow   = (u16*)alloc((size_t)N_NODES * 256 * 2);     // [n][0:128]=h_sum, [128:256]=h_prod
    u16* hp     = (u16*)alloc((size_t)N_NODES * 128 * 2);

    (void)in_sizes; (void)n_in; (void)out_size; (void)ws_size;

    int nb = (N_NODES + 1023) / 1024;
    hipMemsetAsync(deg2, 0, (size_t)2 * N_NODES * 4, stream);
    k_deg<<<(N_EDGES + 255) / 256, 256, 0, stream>>>(src, dst, out_deg, in_deg);
    k_scan1<<<nb, 256, 0, stream>>>(in_deg, blockSums);
    k_scan2<<<1, 64, 0, stream>>>(blockSums, nb, csr_edge + N_EDGES);
    k_scan3<<<nb, 256, 0, stream>>>(in_deg, out_deg, blockSums, csr_start, cursor, out_scale, in_scale);
    k_scatter<<<(N_EDGES + 255) / 256, 256, 0, stream>>>(src, dst, attr, cursor, csr_edge);
    k_prepw<<<192, 256, 0, stream>>>(w1, w2, v, wvfrag);
    k_prepf<<<(N_NODES * 32 + 255) / 256, 256, 0, stream>>>(feat, out_scale, featb);
    k_gemm<<<1280, 256, 0, stream>>>(featb, wvfrag, w2, hrow);
    k_edge<<<2048, 256, 0, stream>>>(csr_start, in_deg, csr_edge, hrow, bond, out, hp);
    k_final<<<1280, 256, 0, stream>>>(hp, wvfrag + 2 * 16384, in_scale, out);
}

// Round 6
// 413.700 us; speedup vs baseline: 1.5925x; 1.0542x over previous
//
#include <hip/hip_runtime.h>

#define N_NODES 100000
#define N_EDGES 800000

typedef unsigned short u16;
typedef unsigned int u32;
typedef __attribute__((ext_vector_type(8))) short short8;
typedef __attribute__((ext_vector_type(4))) float floatx4;

__device__ __forceinline__ float bf2f(u16 u) {
    union { u32 i; float f; } v; v.i = ((u32)u) << 16; return v.f;
}
__device__ __forceinline__ float bflo(u32 u) {
    union { u32 i; float f; } v; v.i = u << 16; return v.f;
}
__device__ __forceinline__ float bfhi(u32 u) {
    union { u32 i; float f; } v; v.i = u & 0xFFFF0000u; return v.f;
}
__device__ __forceinline__ u16 f2bf(float f) {
    union { float f; u32 i; } v; v.f = f;
    u32 r = (v.i + 0x7FFFu + ((v.i >> 16) & 1u)) >> 16;
    return (u16)r;
}
__device__ __forceinline__ float fast_tanh(float x) {
    float e = __expf(2.0f * x);
    return 1.0f - 2.0f * __builtin_amdgcn_rcpf(e + 1.0f);
}

// ---------------- degree + CSR build ----------------

__global__ void k_deg(const int* __restrict__ src, const int* __restrict__ dst,
                      int* out_deg, int* in_deg) {
    int e = blockIdx.x * 256 + threadIdx.x;
    if (e < N_EDGES) {
        atomicAdd(&out_deg[src[e]], 1);
        atomicAdd(&in_deg[dst[e]], 1);
    }
}

__global__ void k_scan1(const int* __restrict__ in_deg, int* blockSums) {
    __shared__ int red[256];
    int t = threadIdx.x;
    int base = blockIdx.x * 1024 + t * 4;
    int s = 0;
#pragma unroll
    for (int j = 0; j < 4; j++) { int idx = base + j; if (idx < N_NODES) s += in_deg[idx]; }
    red[t] = s; __syncthreads();
    for (int off = 128; off > 0; off >>= 1) {
        if (t < off) red[t] += red[t + off];
        __syncthreads();
    }
    if (t == 0) blockSums[blockIdx.x] = red[0];
}

// scan3 computes its own exclusive block prefix from blockSums (k_scan2 eliminated)
__global__ void k_scan3(const int* __restrict__ in_deg, const int* __restrict__ out_deg,
                        const int* __restrict__ blockSums,
                        int* csr_start, int* cursor, float* out_scale, float* in_scale) {
    __shared__ int sc[256];
    __shared__ int boff;
    int t = threadIdx.x;
    if (t < 64) {
        int s = 0;
        for (int i = t; i < blockIdx.x; i += 64) s += blockSums[i];
#pragma unroll
        for (int o = 32; o > 0; o >>= 1) s += __shfl_down(s, o);
        if (t == 0) boff = s;
    }
    int base = blockIdx.x * 1024 + t * 4;
    int d[4]; int s = 0;
#pragma unroll
    for (int j = 0; j < 4; j++) { int idx = base + j; d[j] = (idx < N_NODES) ? in_deg[idx] : 0; s += d[j]; }
    sc[t] = s; __syncthreads();
    for (int off = 1; off < 256; off <<= 1) {
        int v = (t >= off) ? sc[t - off] : 0;
        __syncthreads();
        sc[t] += v;
        __syncthreads();
    }
    int excl = sc[t] - s;
    int run = boff + excl;
#pragma unroll
    for (int j = 0; j < 4; j++) {
        int idx = base + j;
        if (idx < N_NODES) {
            csr_start[idx] = run; cursor[idx] = run; run += d[j];
            int od = out_deg[idx]; if (od < 1) od = 1;
            out_scale[idx] = rsqrtf((float)od);
            int id = d[j]; if (id < 1) id = 1;
            in_scale[idx] = rsqrtf((float)id);
        }
    }
}

__global__ void k_scatter(const int* __restrict__ src, const int* __restrict__ dst,
                          const int* __restrict__ attr, int* cursor, int* csr_edge) {
    int e = blockIdx.x * 256 + threadIdx.x;
    if (e < N_EDGES) {
        int d = dst[e];
        int pos = atomicAdd(&cursor[d], 1);
        csr_edge[pos] = (src[e] << 5) | attr[e];
    }
}

// ---------------- prep: weights -> bf16 B-frag layout; feat*scale -> bf16 ----------------
// frag layout [m][ot][ks][lane][j]: element (k,o): ot=o>>4, ks=k>>5, quad=(k>>3)&3, j=k&7, lane=(quad<<4)|(o&15)

__global__ void k_prepw(const float* __restrict__ w1, const float* __restrict__ w2,
                        const float* __restrict__ v, u16* __restrict__ wvfrag) {
    int idx = blockIdx.x * 256 + threadIdx.x;   // 3*16384
    if (idx >= 3 * 16384) return;
    int m = idx >> 14, r = idx & 16383;
    int k = r >> 7, o = r & 127;
    float val = (m == 0) ? w1[k * 128 + o] : (m == 1) ? w2[k * 128 + o] : v[k * 128 + o];
    int ot = o >> 4, ks = k >> 5, quad = (k >> 3) & 3, j = k & 7;
    int lane = (quad << 4) | (o & 15);
    wvfrag[(((m * 8 + ot) * 4 + ks) * 64 + lane) * 8 + j] = f2bf(val);
}

__global__ void k_prepf(const float* __restrict__ feat, const float* __restrict__ out_scale,
                        u16* __restrict__ featb) {
    int gid = blockIdx.x * 256 + threadIdx.x;   // N*32
    int n = gid >> 5, c = gid & 31;
    if (n >= N_NODES) return;
    float s = out_scale[n];
    float4 f = *(const float4*)(feat + n * 128 + c * 4);
    uint2 pv;
    pv.x = (u32)f2bf(f.x * s) | ((u32)f2bf(f.y * s) << 16);
    pv.y = (u32)f2bf(f.z * s) | ((u32)f2bf(f.w * s) << 16);
    *(uint2*)(featb + n * 128 + c * 4) = pv;
}

// ---------------- node GEMMs -> hrow interleaved layout ----------------
// hrow row (256 u16): lane l's 8 bytes at u16-idx 4l = [sum(2l), sum(2l+1), prod(2l), prod(2l+1)]
// channel o: sum -> 4*(o>>1) + (o&1), prod -> 4*(o>>1) + 2 + (o&1).
// per-ot accumulator (4 VGPRs) + immediate epilogue => spill-proof at the 64-VGPR tier.

__global__ __launch_bounds__(256) void k_gemm(const u16* __restrict__ featb,
                                              const u16* __restrict__ wvfrag,
                                              const float* __restrict__ w2,
                                              u16* __restrict__ hrow) {
    __shared__ u16 ldsw[16384];  // 32 KB
    int m = blockIdx.x & 1;
    const u16* wsrc = wvfrag + m * 16384;
    for (int i = threadIdx.x; i < 2048; i += 256)
        ((ulonglong2*)ldsw)[i] = ((const ulonglong2*)wsrc)[i];
    __syncthreads();
    int wave = threadIdx.x >> 6, lane = threadIdx.x & 63;
    int quad = lane >> 4, l15 = lane & 15;
    const float* bias = w2 + 128 * 128;
    const int NT = (N_NODES + 63) / 64;
    int stride = gridDim.x >> 1;
    for (int tile = blockIdx.x >> 1; tile < NT; tile += stride) {
        int nb = tile * 64 + wave * 16;
        int anode = nb + l15; if (anode >= N_NODES) anode = N_NODES - 1;
        short8 a[4];
#pragma unroll
        for (int ks = 0; ks < 4; ks++)
            a[ks] = *(const short8*)(featb + anode * 128 + ks * 32 + quad * 8);
#pragma unroll
        for (int ot = 0; ot < 8; ot++) {
            floatx4 acc = (floatx4){0.f, 0.f, 0.f, 0.f};
#pragma unroll
            for (int ks = 0; ks < 4; ks++) {
                short8 b = *(const short8*)&ldsw[((ot * 4 + ks) * 64 + lane) * 8];
                acc = __builtin_amdgcn_mfma_f32_16x16x32_bf16(a[ks], b, acc, 0, 0, 0);
            }
            int o = ot * 16 + l15;
            int opos = ((o >> 1) << 2) + (o & 1);
            if (m == 0) {
#pragma unroll
                for (int r = 0; r < 4; r++) {
                    int node = nb + quad * 4 + r;
                    if (node < N_NODES) hrow[node * 256 + opos] = f2bf(acc[r]);
                }
            } else {
                float bs = bias[o];
#pragma unroll
                for (int r = 0; r < 4; r++) {
                    int node = nb + quad * 4 + r;
                    if (node < N_NODES) hrow[node * 256 + opos + 2] = f2bf(fast_tanh(acc[r] + bs));
                }
            }
        }
    }
}

// ---------------- edge stage ----------------
// one node per wave; keys for up to 64 edges loaded lane-parallel once, then distributed via
// readlane (SALU, no memory dep) -> gather bases are scalar. One dwordx2 hrow gather +
// one dwordx2 bond load per edge, 2-deep rolling pipeline.

__global__ __launch_bounds__(256, 8) void k_edge(const int* __restrict__ csr_start, const int* __restrict__ in_deg,
                                                 const int* __restrict__ csr_edge,
                                                 const u16* __restrict__ hrow,
                                                 const float* __restrict__ bond_emb,
                                                 float* __restrict__ out_hs, u16* __restrict__ hp) {
    int wid = (blockIdx.x * 256 + threadIdx.x) >> 6;
    int lane = threadIdx.x & 63;
    int nwaves = (gridDim.x * 256) >> 6;
    for (int n = wid; n < N_NODES; n += nwaves) {
        int start = csr_start[n], deg = in_deg[n];
        float s0 = 0.f, s1 = 0.f, p0 = 1.f, p1 = 1.f;
        for (int base = 0; base < deg; base += 64) {
            int cnt = deg - base; if (cnt > 64) cnt = 64;
            int li = lane < cnt ? lane : cnt - 1;
            int pkv = csr_edge[start + base + li];
            int pk0 = __builtin_amdgcn_readlane(pkv, 0);
            int pk1 = __builtin_amdgcn_readlane(pkv, cnt > 1 ? 1 : 0);
            uint2 hA = *(const uint2*)(hrow + (pk0 >> 5) * 256 + 4 * lane);
            float2 eA = *(const float2*)(bond_emb + (pk0 & 31) * 128 + 2 * lane);
            uint2 hB = *(const uint2*)(hrow + (pk1 >> 5) * 256 + 4 * lane);
            float2 eB = *(const float2*)(bond_emb + (pk1 & 31) * 128 + 2 * lane);
            for (int j = 0; j < cnt; j++) {
                int j2 = j + 2; if (j2 >= cnt) j2 = cnt - 1;
                int pk = __builtin_amdgcn_readlane(pkv, j2);
                uint2 hC = *(const uint2*)(hrow + (pk >> 5) * 256 + 4 * lane);
                float2 eC = *(const float2*)(bond_emb + (pk & 31) * 128 + 2 * lane);
                s0 += bflo(hA.x) * eA.x;
                s1 += bfhi(hA.x) * eA.y;
                p0 *= bflo(hA.y) * eA.x;
                p1 *= bfhi(hA.y) * eA.y;
                hA = hB; eA = eB; hB = hC; eB = eC;
            }
        }
        float2 sv; sv.x = s0; sv.y = s1;
        *(float2*)(out_hs + n * 128 + 2 * lane) = sv;
        u32 pp = ((u32)f2bf(p1) << 16) | (u32)f2bf(p0);
        *(u32*)(hp + n * 128 + 2 * lane) = pp;
    }
}

// ---------------- final: out = (hs + hp@v) * in_scale ; hs lives in d_out ----------------

__global__ __launch_bounds__(256) void k_final(const u16* __restrict__ hp,
                                               const u16* __restrict__ vfrag,
                                               const float* __restrict__ in_scale,
                                               float* __restrict__ out) {
    __shared__ u16 ldsw[16384];  // 32 KB
    for (int i = threadIdx.x; i < 2048; i += 256)
        ((ulonglong2*)ldsw)[i] = ((const ulonglong2*)vfrag)[i];
    __syncthreads();
    int wave = threadIdx.x >> 6, lane = threadIdx.x & 63;
    int quad = lane >> 4, l15 = lane & 15;
    const int NT = (N_NODES + 63) / 64;
    for (int tile = blockIdx.x; tile < NT; tile += gridDim.x) {
        int nb = tile * 64 + wave * 16;
        int anode = nb + l15; if (anode >= N_NODES) anode = N_NODES - 1;
        short8 a[4];
#pragma unroll
        for (int ks = 0; ks < 4; ks++)
            a[ks] = *(const short8*)(hp + anode * 128 + ks * 32 + quad * 8);
#pragma unroll
        for (int ot = 0; ot < 8; ot++) {
            floatx4 acc = (floatx4){0.f, 0.f, 0.f, 0.f};
#pragma unroll
            for (int ks = 0; ks < 4; ks++) {
                short8 b = *(const short8*)&ldsw[((ot * 4 + ks) * 64 + lane) * 8];
                acc = __builtin_amdgcn_mfma_f32_16x16x32_bf16(a[ks], b, acc, 0, 0, 0);
            }
            int o = ot * 16 + l15;
#pragma unroll
            for (int r = 0; r < 4; r++) {
                int node = nb + quad * 4 + r;
                if (node < N_NODES) {
                    float scl = in_scale[node];
                    float hsv = out[node * 128 + o];          // hs, written by k_edge
                    out[node * 128 + o] = (acc[r] + hsv) * scl;
                }
            }
        }
    }
}

extern "C" void kernel_launch(void* const* d_in, const int* in_sizes, int n_in,
                              void* d_out, int out_size, void* d_ws, size_t ws_size,
                              hipStream_t stream) {
    const float* feat = (const float*)d_in[0];
    const int* src = (const int*)d_in[1];
    const int* dst = (const int*)d_in[2];
    const int* attr = (const int*)d_in[3];
    const float* w1 = (const float*)d_in[4];
    const float* w2 = (const float*)d_in[5];
    const float* v = (const float*)d_in[6];
    const float* bond = (const float*)d_in[7];
    float* out = (float*)d_out;

    char* ws = (char*)d_ws;
    size_t off = 0;
    auto alloc = [&](size_t bytes) -> char* {
        char* p = ws + off; off += (bytes + 255) & ~(size_t)255; return p;
    };
    int* deg2      = (int*)alloc((size_t)2 * N_NODES * 4);   // out_deg | in_deg, one memset
    int* out_deg   = deg2;
    int* in_deg    = deg2 + N_NODES;
    int* csr_start = (int*)alloc((size_t)N_NODES * 4);
    int* cursor    = (int*)alloc((size_t)N_NODES * 4);
    int* blockSums = (int*)alloc(1024 * 4);
    float* out_scale = (float*)alloc((size_t)N_NODES * 4);
    float* in_scale  = (float*)alloc((size_t)N_NODES * 4);
    int* csr_edge  = (int*)alloc((size_t)N_EDGES * 4);
    u16* wvfrag = (u16*)alloc((size_t)3 * 16384 * 2);         // w1|w2|v bf16 frags
    u16* featb  = (u16*)alloc((size_t)N_NODES * 128 * 2);     // feat*out_scale, bf16
    u16* hrow   = (u16*)alloc((size_t)N_NODES * 256 * 2);     // interleaved sum/prod
    u16* hp     = (u16*)alloc((size_t)N_NODES * 128 * 2);

    (void)in_sizes; (void)n_in; (void)out_size; (void)ws_size;

    int nb = (N_NODES + 1023) / 1024;
    hipMemsetAsync(deg2, 0, (size_t)2 * N_NODES * 4, stream);
    k_deg<<<(N_EDGES + 255) / 256, 256, 0, stream>>>(src, dst, out_deg, in_deg);
    k_scan1<<<nb, 256, 0, stream>>>(in_deg, blockSums);
    k_scan3<<<nb, 256, 0, stream>>>(in_deg, out_deg, blockSums, csr_start, cursor, out_scale, in_scale);
    k_scatter<<<(N_EDGES + 255) / 256, 256, 0, stream>>>(src, dst, attr, cursor, csr_edge);
    k_prepw<<<192, 256, 0, stream>>>(w1, w2, v, wvfrag);
    k_prepf<<<(N_NODES * 32 + 255) / 256, 256, 0, stream>>>(feat, out_scale, featb);
    k_gemm<<<1280, 256, 0, stream>>>(featb, wvfrag, w2, hrow);
    k_edge<<<2048, 256, 0, stream>>>(csr_start, in_deg, csr_edge, hrow, bond, out, hp);
    k_final<<<1280, 256, 0, stream>>>(hp, wvfrag + 2 * 16384, in_scale, out);
}

// Round 7
// 406.935 us; speedup vs baseline: 1.6190x; 1.0166x over previous
//
#include <hip/hip_runtime.h>

#define N_NODES 100000
#define N_EDGES 800000

typedef unsigned short u16;
typedef unsigned int u32;
typedef __attribute__((ext_vector_type(8))) short short8;
typedef __attribute__((ext_vector_type(4))) float floatx4;

__device__ __forceinline__ float bf2f(u16 u) {
    union { u32 i; float f; } v; v.i = ((u32)u) << 16; return v.f;
}
__device__ __forceinline__ float bflo(u32 u) {
    union { u32 i; float f; } v; v.i = u << 16; return v.f;
}
__device__ __forceinline__ float bfhi(u32 u) {
    union { u32 i; float f; } v; v.i = u & 0xFFFF0000u; return v.f;
}
__device__ __forceinline__ u16 f2bf(float f) {
    union { float f; u32 i; } v; v.f = f;
    u32 r = (v.i + 0x7FFFu + ((v.i >> 16) & 1u)) >> 16;
    return (u16)r;
}
__device__ __forceinline__ float fast_tanh(float x) {
    float e = __expf(2.0f * x);
    return 1.0f - 2.0f * __builtin_amdgcn_rcpf(e + 1.0f);
}

// ---------------- degree + CSR build ----------------

__global__ void k_deg(const int* __restrict__ src, const int* __restrict__ dst,
                      int* out_deg, int* in_deg) {
    int e = blockIdx.x * 256 + threadIdx.x;
    if (e < N_EDGES) {
        atomicAdd(&out_deg[src[e]], 1);
        atomicAdd(&in_deg[dst[e]], 1);
    }
}

__global__ void k_scan1(const int* __restrict__ in_deg, int* blockSums) {
    __shared__ int red[256];
    int t = threadIdx.x;
    int base = blockIdx.x * 1024 + t * 4;
    int s = 0;
#pragma unroll
    for (int j = 0; j < 4; j++) { int idx = base + j; if (idx < N_NODES) s += in_deg[idx]; }
    red[t] = s; __syncthreads();
    for (int off = 128; off > 0; off >>= 1) {
        if (t < off) red[t] += red[t + off];
        __syncthreads();
    }
    if (t == 0) blockSums[blockIdx.x] = red[0];
}

// scan3 computes its own exclusive block prefix from blockSums
__global__ void k_scan3(const int* __restrict__ in_deg, const int* __restrict__ out_deg,
                        const int* __restrict__ blockSums,
                        int* csr_start, int* cursor, float* out_scale, float* in_scale) {
    __shared__ int sc[256];
    __shared__ int boff;
    int t = threadIdx.x;
    if (t < 64) {
        int s = 0;
        for (int i = t; i < blockIdx.x; i += 64) s += blockSums[i];
#pragma unroll
        for (int o = 32; o > 0; o >>= 1) s += __shfl_down(s, o);
        if (t == 0) boff = s;
    }
    int base = blockIdx.x * 1024 + t * 4;
    int d[4]; int s = 0;
#pragma unroll
    for (int j = 0; j < 4; j++) { int idx = base + j; d[j] = (idx < N_NODES) ? in_deg[idx] : 0; s += d[j]; }
    sc[t] = s; __syncthreads();
    for (int off = 1; off < 256; off <<= 1) {
        int v = (t >= off) ? sc[t - off] : 0;
        __syncthreads();
        sc[t] += v;
        __syncthreads();
    }
    int excl = sc[t] - s;
    int run = boff + excl;
#pragma unroll
    for (int j = 0; j < 4; j++) {
        int idx = base + j;
        if (idx < N_NODES) {
            csr_start[idx] = run; cursor[idx] = run; run += d[j];
            int od = out_deg[idx]; if (od < 1) od = 1;
            out_scale[idx] = rsqrtf((float)od);
            int id = d[j]; if (id < 1) id = 1;
            in_scale[idx] = rsqrtf((float)id);
        }
    }
}

// ---------------- fused mid stage: scatter + weight-frag prep + feat prep ----------------
// blocks [0,3125): scatter; [3125,3317): prepw; [3317,15817): prepf. All depend only on scan3.
// frag layout [m][ot][ks][lane][j]: ot=o>>4, ks=k>>5, quad=(k>>3)&3, j=k&7, lane=(quad<<4)|(o&15)

#define NB_SCAT 3125
#define NB_PREPW 192
__global__ void k_mid(const int* __restrict__ src, const int* __restrict__ dst,
                      const int* __restrict__ attr, int* cursor, int* csr_edge,
                      const float* __restrict__ w1, const float* __restrict__ w2,
                      const float* __restrict__ v, u16* __restrict__ wvfrag,
                      const float* __restrict__ feat, const float* __restrict__ out_scale,
                      u16* __restrict__ featb) {
    int b = blockIdx.x;
    if (b < NB_SCAT) {
        int e = b * 256 + threadIdx.x;
        if (e < N_EDGES) {
            int d = dst[e];
            int pos = atomicAdd(&cursor[d], 1);
            csr_edge[pos] = (src[e] << 5) | attr[e];
        }
    } else if (b < NB_SCAT + NB_PREPW) {
        int idx = (b - NB_SCAT) * 256 + threadIdx.x;   // 3*16384
        if (idx < 3 * 16384) {
            int m = idx >> 14, r = idx & 16383;
            int k = r >> 7, o = r & 127;
            float val = (m == 0) ? w1[k * 128 + o] : (m == 1) ? w2[k * 128 + o] : v[k * 128 + o];
            int ot = o >> 4, ks = k >> 5, quad = (k >> 3) & 3, j = k & 7;
            int lane = (quad << 4) | (o & 15);
            wvfrag[(((m * 8 + ot) * 4 + ks) * 64 + lane) * 8 + j] = f2bf(val);
        }
    } else {
        int gid = (b - NB_SCAT - NB_PREPW) * 256 + threadIdx.x;   // N*32
        int n = gid >> 5, c = gid & 31;
        if (n < N_NODES) {
            float s = out_scale[n];
            float4 f = *(const float4*)(feat + n * 128 + c * 4);
            uint2 pv;
            pv.x = (u32)f2bf(f.x * s) | ((u32)f2bf(f.y * s) << 16);
            pv.y = (u32)f2bf(f.z * s) | ((u32)f2bf(f.w * s) << 16);
            *(uint2*)(featb + n * 128 + c * 4) = pv;
        }
    }
}

// ---------------- node GEMMs -> hrow interleaved layout ----------------
// hrow row (256 u16): lane l's 8 bytes at u16-idx 4l = [sum(2l), sum(2l+1), prod(2l), prod(2l+1)]
// per-ot accumulator (4 VGPRs) + immediate epilogue => spill-proof at the 64-VGPR tier.

__global__ __launch_bounds__(256) void k_gemm(const u16* __restrict__ featb,
                                              const u16* __restrict__ wvfrag,
                                              const float* __restrict__ w2,
                                              u16* __restrict__ hrow) {
    __shared__ u16 ldsw[16384];  // 32 KB
    int m = blockIdx.x & 1;
    const u16* wsrc = wvfrag + m * 16384;
    for (int i = threadIdx.x; i < 2048; i += 256)
        ((ulonglong2*)ldsw)[i] = ((const ulonglong2*)wsrc)[i];
    __syncthreads();
    int wave = threadIdx.x >> 6, lane = threadIdx.x & 63;
    int quad = lane >> 4, l15 = lane & 15;
    const float* bias = w2 + 128 * 128;
    const int NT = (N_NODES + 63) / 64;
    int stride = gridDim.x >> 1;
    for (int tile = blockIdx.x >> 1; tile < NT; tile += stride) {
        int nb = tile * 64 + wave * 16;
        int anode = nb + l15; if (anode >= N_NODES) anode = N_NODES - 1;
        short8 a[4];
#pragma unroll
        for (int ks = 0; ks < 4; ks++)
            a[ks] = *(const short8*)(featb + anode * 128 + ks * 32 + quad * 8);
#pragma unroll
        for (int ot = 0; ot < 8; ot++) {
            floatx4 acc = (floatx4){0.f, 0.f, 0.f, 0.f};
#pragma unroll
            for (int ks = 0; ks < 4; ks++) {
                short8 b = *(const short8*)&ldsw[((ot * 4 + ks) * 64 + lane) * 8];
                acc = __builtin_amdgcn_mfma_f32_16x16x32_bf16(a[ks], b, acc, 0, 0, 0);
            }
            int o = ot * 16 + l15;
            int opos = ((o >> 1) << 2) + (o & 1);
            if (m == 0) {
#pragma unroll
                for (int r = 0; r < 4; r++) {
                    int node = nb + quad * 4 + r;
                    if (node < N_NODES) hrow[node * 256 + opos] = f2bf(acc[r]);
                }
            } else {
                float bs = bias[o];
#pragma unroll
                for (int r = 0; r < 4; r++) {
                    int node = nb + quad * 4 + r;
                    if (node < N_NODES) hrow[node * 256 + opos + 2] = f2bf(fast_tanh(acc[r] + bs));
                }
            }
        }
    }
}

// ---------------- edge stage: TWO node streams per wave (2x MLP) ----------------
// keys lane-parallel + readlane (scalar gather bases); guarded depth-2 pipeline per stream.

__global__ __launch_bounds__(256, 8) void k_edge(const int* __restrict__ csr_start, const int* __restrict__ in_deg,
                                                 const int* __restrict__ csr_edge,
                                                 const u16* __restrict__ hrow,
                                                 const float* __restrict__ bond_emb,
                                                 float* __restrict__ out_hs, u16* __restrict__ hp) {
    int wid = (blockIdx.x * 256 + threadIdx.x) >> 6;
    int lane = threadIdx.x & 63;
    int nwaves = (gridDim.x * 256) >> 6;
    const int NPAIR = N_NODES / 2;
    uint2 hC0 = {0, 0}, hC1 = {0, 0};
    float2 eC0 = {0.f, 0.f}, eC1 = {0.f, 0.f};
    for (int pr = wid; pr < NPAIR; pr += nwaves) {
        int n0 = pr * 2, n1 = n0 + 1;
        int st0 = csr_start[n0];
        int2 dd = *(const int2*)(in_deg + n0);     // n0 even -> 8B aligned
        int d0 = dd.x, d1 = dd.y;
        int st1 = st0 + d0;                         // CSR prefix property
        float as0 = 0.f, as1 = 0.f, ap0 = 1.f, ap1 = 1.f;
        float bs0 = 0.f, bs1 = 0.f, bp0 = 1.f, bp1 = 1.f;
        int b0 = 0, b1 = 0;
        while (b0 < d0 || b1 < d1) {
            int c0 = d0 - b0; c0 = c0 < 0 ? 0 : (c0 > 64 ? 64 : c0);
            int c1 = d1 - b1; c1 = c1 < 0 ? 0 : (c1 > 64 ? 64 : c1);
            int pkv0 = 0, pkv1 = 0;
            if (c0 > 0) { int li = lane < c0 ? lane : c0 - 1; pkv0 = csr_edge[st0 + b0 + li]; }
            if (c1 > 0) { int li = lane < c1 ? lane : c1 - 1; pkv1 = csr_edge[st1 + b1 + li]; }
            uint2 hA0 = hC0, hB0 = hC0, hA1 = hC1, hB1 = hC1;
            float2 eA0 = eC0, eB0 = eC0, eA1 = eC1, eB1 = eC1;
            if (c0 > 0) {
                int pk = __builtin_amdgcn_readlane(pkv0, 0);
                hA0 = *(const uint2*)(hrow + (pk >> 5) * 256 + 4 * lane);
                eA0 = *(const float2*)(bond_emb + (pk & 31) * 128 + 2 * lane);
                if (c0 > 1) {
                    pk = __builtin_amdgcn_readlane(pkv0, 1);
                    hB0 = *(const uint2*)(hrow + (pk >> 5) * 256 + 4 * lane);
                    eB0 = *(const float2*)(bond_emb + (pk & 31) * 128 + 2 * lane);
                }
            }
            if (c1 > 0) {
                int pk = __builtin_amdgcn_readlane(pkv1, 0);
                hA1 = *(const uint2*)(hrow + (pk >> 5) * 256 + 4 * lane);
                eA1 = *(const float2*)(bond_emb + (pk & 31) * 128 + 2 * lane);
                if (c1 > 1) {
                    pk = __builtin_amdgcn_readlane(pkv1, 1);
                    hB1 = *(const uint2*)(hrow + (pk >> 5) * 256 + 4 * lane);
                    eB1 = *(const float2*)(bond_emb + (pk & 31) * 128 + 2 * lane);
                }
            }
            int cm = c0 > c1 ? c0 : c1;
            for (int j = 0; j < cm; j++) {
                int jn = j + 2;
                if (jn < c0) {
                    int pk = __builtin_amdgcn_readlane(pkv0, jn);
                    hC0 = *(const uint2*)(hrow + (pk >> 5) * 256 + 4 * lane);
                    eC0 = *(const float2*)(bond_emb + (pk & 31) * 128 + 2 * lane);
                }
                if (jn < c1) {
                    int pk = __builtin_amdgcn_readlane(pkv1, jn);
                    hC1 = *(const uint2*)(hrow + (pk >> 5) * 256 + 4 * lane);
                    eC1 = *(const float2*)(bond_emb + (pk & 31) * 128 + 2 * lane);
                }
                if (j < c0) {
                    as0 += bflo(hA0.x) * eA0.x;
                    as1 += bfhi(hA0.x) * eA0.y;
                    ap0 *= bflo(hA0.y) * eA0.x;
                    ap1 *= bfhi(hA0.y) * eA0.y;
                    hA0 = hB0; eA0 = eB0; hB0 = hC0; eB0 = eC0;
                }
                if (j < c1) {
                    bs0 += bflo(hA1.x) * eA1.x;
                    bs1 += bfhi(hA1.x) * eA1.y;
                    bp0 *= bflo(hA1.y) * eA1.x;
                    bp1 *= bfhi(hA1.y) * eA1.y;
                    hA1 = hB1; eA1 = eB1; hB1 = hC1; eB1 = eC1;
                }
            }
            b0 += 64; b1 += 64;
        }
        float2 sv0; sv0.x = as0; sv0.y = as1;
        float2 sv1; sv1.x = bs0; sv1.y = bs1;
        *(float2*)(out_hs + n0 * 128 + 2 * lane) = sv0;
        *(float2*)(out_hs + n1 * 128 + 2 * lane) = sv1;
        *(u32*)(hp + n0 * 128 + 2 * lane) = ((u32)f2bf(ap1) << 16) | (u32)f2bf(ap0);
        *(u32*)(hp + n1 * 128 + 2 * lane) = ((u32)f2bf(bp1) << 16) | (u32)f2bf(bp0);
    }
}

// ---------------- final: out = (hs + hp@v) * in_scale ; hs lives in d_out ----------------

__global__ __launch_bounds__(256) void k_final(const u16* __restrict__ hp,
                                               const u16* __restrict__ vfrag,
                                               const float* __restrict__ in_scale,
                                               float* __restrict__ out) {
    __shared__ u16 ldsw[16384];  // 32 KB
    for (int i = threadIdx.x; i < 2048; i += 256)
        ((ulonglong2*)ldsw)[i] = ((const ulonglong2*)vfrag)[i];
    __syncthreads();
    int wave = threadIdx.x >> 6, lane = threadIdx.x & 63;
    int quad = lane >> 4, l15 = lane & 15;
    const int NT = (N_NODES + 63) / 64;
    for (int tile = blockIdx.x; tile < NT; tile += gridDim.x) {
        int nb = tile * 64 + wave * 16;
        int anode = nb + l15; if (anode >= N_NODES) anode = N_NODES - 1;
        short8 a[4];
#pragma unroll
        for (int ks = 0; ks < 4; ks++)
            a[ks] = *(const short8*)(hp + anode * 128 + ks * 32 + quad * 8);
#pragma unroll
        for (int ot = 0; ot < 8; ot++) {
            floatx4 acc = (floatx4){0.f, 0.f, 0.f, 0.f};
#pragma unroll
            for (int ks = 0; ks < 4; ks++) {
                short8 b = *(const short8*)&ldsw[((ot * 4 + ks) * 64 + lane) * 8];
                acc = __builtin_amdgcn_mfma_f32_16x16x32_bf16(a[ks], b, acc, 0, 0, 0);
            }
            int o = ot * 16 + l15;
#pragma unroll
            for (int r = 0; r < 4; r++) {
                int node = nb + quad * 4 + r;
                if (node < N_NODES) {
                    float scl = in_scale[node];
                    float hsv = out[node * 128 + o];          // hs, written by k_edge
                    out[node * 128 + o] = (acc[r] + hsv) * scl;
                }
            }
        }
    }
}

extern "C" void kernel_launch(void* const* d_in, const int* in_sizes, int n_in,
                              void* d_out, int out_size, void* d_ws, size_t ws_size,
                              hipStream_t stream) {
    const float* feat = (const float*)d_in[0];
    const int* src = (const int*)d_in[1];
    const int* dst = (const int*)d_in[2];
    const int* attr = (const int*)d_in[3];
    const float* w1 = (const float*)d_in[4];
    const float* w2 = (const float*)d_in[5];
    const float* v = (const float*)d_in[6];
    const float* bond = (const float*)d_in[7];
    float* out = (float*)d_out;

    char* ws = (char*)d_ws;
    size_t off = 0;
    auto alloc = [&](size_t bytes) -> char* {
        char* p = ws + off; off += (bytes + 255) & ~(size_t)255; return p;
    };
    int* deg2      = (int*)alloc((size_t)2 * N_NODES * 4);   // out_deg | in_deg, one memset
    int* out_deg   = deg2;
    int* in_deg    = deg2 + N_NODES;
    int* csr_start = (int*)alloc((size_t)N_NODES * 4);
    int* cursor    = (int*)alloc((size_t)N_NODES * 4);
    int* blockSums = (int*)alloc(1024 * 4);
    float* out_scale = (float*)alloc((size_t)N_NODES * 4);
    float* in_scale  = (float*)alloc((size_t)N_NODES * 4);
    int* csr_edge  = (int*)alloc((size_t)N_EDGES * 4);
    u16* wvfrag = (u16*)alloc((size_t)3 * 16384 * 2);         // w1|w2|v bf16 frags
    u16* featb  = (u16*)alloc((size_t)N_NODES * 128 * 2);     // feat*out_scale, bf16
    u16* hrow   = (u16*)alloc((size_t)N_NODES * 256 * 2);     // interleaved sum/prod
    u16* hp     = (u16*)alloc((size_t)N_NODES * 128 * 2);

    (void)in_sizes; (void)n_in; (void)out_size; (void)ws_size;

    int nb = (N_NODES + 1023) / 1024;
    hipMemsetAsync(deg2, 0, (size_t)2 * N_NODES * 4, stream);
    k_deg<<<(N_EDGES + 255) / 256, 256, 0, stream>>>(src, dst, out_deg, in_deg);
    k_scan1<<<nb, 256, 0, stream>>>(in_deg, blockSums);
    k_scan3<<<nb, 256, 0, stream>>>(in_deg, out_deg, blockSums, csr_start, cursor, out_scale, in_scale);
    k_mid<<<NB_SCAT + NB_PREPW + 12500, 256, 0, stream>>>(src, dst, attr, cursor, csr_edge,
                                                          w1, w2, v, wvfrag, feat, out_scale, featb);
    k_gemm<<<1280, 256, 0, stream>>>(featb, wvfrag, w2, hrow);
    k_edge<<<2048, 256, 0, stream>>>(csr_start, in_deg, csr_edge, hrow, bond, out, hp);
    k_final<<<1280, 256, 0, stream>>>(hp, wvfrag + 2 * 16384, in_scale, out);
}